// Round 7
// baseline (21846.652 us; speedup 1.0000x reference)
//
#include <hip/hip_runtime.h>
#include <hip/hip_cooperative_groups.h>
#include <math.h>

namespace cg = cooperative_groups;

typedef _Float16 f16;
typedef __attribute__((ext_vector_type(8))) _Float16 f16x8;
typedef __attribute__((ext_vector_type(4))) float f32x4;

#define Bsz 256
#define Tsz 196
#define Fsz 263
#define TFs (Tsz*Fsz)   // 51548
#define SX  1312        // X row stride (288 frame-pad + 1024 h)
#define KCH 41          // 1312/32 k-chunks
#define LOSC 2048.0f
#define LOINV 0.00048828125f

// ---------------- ws layout (BYTE offsets) ----------------
#define OFF_WALLHI 0u            // packed f16 weights hi: 41*64*4096 B
#define OFF_WALLLO 10747904u     // lo (x2048)
// phase-1 alias: WihT fp32 (16.8MB) lives at 0, freed before pack_wall
#define OFF_PART   21495808u     // loop: partial [8][256][320] f32 (pre: Wcomb alias)
#define OFF_XHI0   26214400u     // pre: cgj alias (4MB)
#define OFF_XLO0   26886144u
#define OFF_XHI1   27557888u
#define OFF_XLO1   28229632u
#define OFF_CGP    30408704u     // constG permuted fp32 [256][4096] = 4MB
#define OFF_L2PH   34603008u     // lin2 packed hi: 32*5*4096 B
#define OFF_L2PL   35258368u
#define OFF_LIN1T  35913728u     // [263][512] f32
#define OFF_LTWT   36452352u     // [768][512] f32
#define OFF_TEXTE  38025216u     // [256][512] f32
#define OFF_BIASG  38549504u     // [4096] f32
#define OFF_WCT    38565888u     // WcombT fp32 [4096][288] = 4718592 B
#define WS_BYTES   43284480u

// ---------------- helpers ----------------
__device__ __forceinline__ void glds16(const void* g, void* l) {
    __builtin_amdgcn_global_load_lds(
        (const __attribute__((address_space(1))) void*)g,
        (__attribute__((address_space(3))) void*)l, 16, 0, 0);
}
__device__ __forceinline__ float sigm(float x) { return 1.f / (1.f + expf(-x)); }
__device__ __forceinline__ void split16(float x, f16& hi, f16& lo) {
    hi = (f16)x;
    lo = (f16)((x - (float)hi) * LOSC);
}
#define MFMA16(a,b,c) __builtin_amdgcn_mfma_f32_16x16x32_f16(a,b,c,0,0,0)

#define WAIT_BAR(N) do { \
    asm volatile("s_waitcnt vmcnt(" #N ")" ::: "memory"); \
    __builtin_amdgcn_s_barrier(); \
    __builtin_amdgcn_sched_barrier(0); \
} while (0)

// ---------------- transpose: src[M][N] -> dst[N][M] ----------------
__global__ __launch_bounds__(256) void tpose(const float* __restrict__ src,
                                             float* __restrict__ dst, int M, int N) {
    __shared__ float tile[32][33];
    int bx = blockIdx.x, by = blockIdx.y;
    int tx = threadIdx.x & 31, ty = threadIdx.x >> 5;
#pragma unroll
    for (int i = 0; i < 4; ++i) {
        int row = by*32 + ty*4 + i, col = bx*32 + tx;
        tile[ty*4+i][tx] = (row < M && col < N) ? src[(size_t)row*N + col] : 0.f;
    }
    __syncthreads();
#pragma unroll
    for (int i = 0; i < 4; ++i) {
        int row = bx*32 + ty*4 + i, col = by*32 + tx;
        if (row < N && col < M) dst[(size_t)row*M + col] = tile[tx][ty*4+i];
    }
}

// ---------------- biasG_j[j] = bih+bhh + sum_e l1b[e]*wih[j][e] ----------------
__global__ __launch_bounds__(256) void biasg_k(const float* __restrict__ bih,
                                               const float* __restrict__ bhh,
                                               const float* __restrict__ l1b,
                                               const float* __restrict__ wih,
                                               float* __restrict__ bg) {
    int j = blockIdx.x*4 + (threadIdx.x >> 6);
    int l = threadIdx.x & 63;
    const float* wr = wih + (size_t)j*1024 + l*8;
    const float* lb = l1b + l*8;
    float s = 0.f;
#pragma unroll
    for (int e = 0; e < 8; ++e) s += lb[e] * wr[e];
#pragma unroll
    for (int off = 32; off; off >>= 1) s += __shfl_down(s, off, 64);
    if (l == 0) bg[j] = bih[j] + bhh[j] + s;
}

// ---------------- generic fp32 NN GEMM (precompute only) ----------------
__global__ __launch_bounds__(256) void nn_gemm(const float* __restrict__ A,
                                               const float* __restrict__ B,
                                               const float* __restrict__ bias,
                                               float* __restrict__ C,
                                               int M, int MA, int N, int K) {
    __shared__ float As[32][33];
    __shared__ float Bs[32][64];
    int tid = threadIdx.x;
    int r0 = blockIdx.y*32, c0 = blockIdx.x*64;
    int tr = tid >> 4, tc = tid & 15;
    float acc[2][4] = {};
    for (int k0 = 0; k0 < K; k0 += 32) {
        int m = tid >> 3, kb = (tid & 7)*4;
        int row = r0 + m;
#pragma unroll
        for (int i = 0; i < 4; ++i)
            As[m][kb+i] = (row < MA) ? A[(size_t)row*K + k0 + kb + i] : 0.f;
#pragma unroll
        for (int i = 0; i < 8; ++i) {
            int fi = i*256 + tid, kk = fi >> 6, cc = fi & 63;
            Bs[kk][cc] = B[(size_t)(k0+kk)*N + c0 + cc];
        }
        __syncthreads();
#pragma unroll
        for (int k = 0; k < 32; ++k) {
            float a0 = As[2*tr][k], a1 = As[2*tr+1][k];
            float b0 = Bs[k][4*tc], b1 = Bs[k][4*tc+1], b2 = Bs[k][4*tc+2], b3 = Bs[k][4*tc+3];
            acc[0][0]+=a0*b0; acc[0][1]+=a0*b1; acc[0][2]+=a0*b2; acc[0][3]+=a0*b3;
            acc[1][0]+=a1*b0; acc[1][1]+=a1*b1; acc[1][2]+=a1*b2; acc[1][3]+=a1*b3;
        }
        __syncthreads();
    }
#pragma unroll
    for (int i = 0; i < 2; ++i) {
        int row = r0 + 2*tr + i;
        if (row < M)
#pragma unroll
            for (int j = 0; j < 4; ++j) {
                int col = c0 + 4*tc + j;
                C[(size_t)row*N + col] = acc[i][j] + (bias ? bias[col] : 0.f);
            }
    }
}

// ---------------- pack Wall (hi/lo f16, glds-linear, swizzled) ----------------
__global__ __launch_bounds__(256) void pack_wall(const float* __restrict__ WcT,
                                                 const float* __restrict__ whh,
                                                 f16* __restrict__ Wh,
                                                 f16* __restrict__ Wl) {
    int q = threadIdx.x;
    int ct = blockIdx.x, kc = blockIdx.y;
    int k = kc*32 + (((q&3) ^ ((q>>3)&3)) << 3);
    int p = ct*64 + (q>>2);
    int j = (p&3)*1024 + (p>>2);
    size_t ob = ((size_t)(kc*64 + ct)*256 + q)*8;
#pragma unroll
    for (int e = 0; e < 8; ++e) {
        int kk = k + e;
        float v = (kk < 288) ? WcT[(size_t)j*288 + kk]
                             : whh[(size_t)j*1024 + (kk - 288)];
        split16(v, Wh[ob+e], Wl[ob+e]);
    }
}

// ---------------- pack lin2 (B[k=u][col=f] = l2w[f][u], pad f>=263 -> 0) ----------------
__global__ __launch_bounds__(256) void pack_lin2(const float* __restrict__ l2w,
                                                 f16* __restrict__ Lh,
                                                 f16* __restrict__ Ll) {
    int q = threadIdx.x;
    int ct = blockIdx.x, kc = blockIdx.y;   // ct<5, kc<32
    int k = kc*32 + (((q&3) ^ ((q>>3)&3)) << 3);
    int f = ct*64 + (q>>2);
    size_t ob = ((size_t)(kc*5 + ct)*256 + q)*8;
#pragma unroll
    for (int e = 0; e < 8; ++e) {
        float v = (f < Fsz) ? l2w[(size_t)f*1024 + k + e] : 0.f;
        split16(v, Lh[ob+e], Ll[ob+e]);
    }
}

// ---------------- permute constG to p = u*4+g layout ----------------
__global__ __launch_bounds__(256) void permute_cg(const float* __restrict__ cj,
                                                  float* __restrict__ cp) {
    int idx = blockIdx.x*256 + threadIdx.x;
    int b = idx >> 12, p = idx & 4095;
    cp[idx] = cj[(b << 12) + ((p & 3) << 10) + (p >> 2)];
}

// ---------------- persistent cooperative kernel: all 196 steps ----------------
// grid 256 blocks x 256 thr (1 block/CU). Per step:
//   A: gates = X@Wall (f16-split MFMA, deep pipeline) + cell update (c in regs)
//   sync; B: split-K x8 proj partials (160 blocks); sync; C: reduce+frame+out; sync
__global__ void __launch_bounds__(256, 1) kmain(
        const float* __restrict__ motions, const float* __restrict__ l2b,
        float* __restrict__ out,
        const f16* __restrict__ Wh, const f16* __restrict__ Wl,
        const f16* __restrict__ Lh, const f16* __restrict__ Ll,
        const float* __restrict__ cgp, float* __restrict__ partial,
        f16* __restrict__ Xh0, f16* __restrict__ Xl0,
        f16* __restrict__ Xh1, f16* __restrict__ Xl1)
{
    cg::grid_group gridg = cg::this_grid();
    __shared__ __attribute__((aligned(16))) char smem[65536];
    const int tid = threadIdx.x;
    const int bid = blockIdx.x;
    const int gid = bid*256 + tid;
    const int ct = bid & 63, rt = bid >> 6;
    const int r0 = rt*64, p0 = ct*64;
    const int l = tid & 63;
    const int wr = (tid >> 7) & 1, wc = (tid >> 6) & 1;
    const int aswz = (((tid&3) ^ ((tid>>3)&3)) << 3);

    int offA[2], offB[2];
#pragma unroll
    for (int R = 0; R < 2; ++R) {
        int g = l >> 4;
        int row = wr*32 + R*16 + (l & 15);
        offA[R] = row*64 + ((g ^ ((row>>1)&3)) & 3)*16;
        int col = wc*32 + R*16 + (l & 15);
        offB[R] = col*64 + ((g ^ ((col>>1)&3)) & 3)*16;
    }
    // proj-unit mapping (phase B, bid < 160): unit = (ks, pct, prt)
    const int pks  = bid / 20;
    const int ptl  = bid - pks*20;
    const int pct  = ptl % 5, prt = ptl / 5;

    // ---- init X0 (frame0 + pads + h=0) ----
    for (int idx = gid; idx < 256*SX; idx += 65536) {
        int b = idx / SX, k = idx - b*SX;
        float v = (k < Fsz) ? motions[(size_t)b*TFs + k] : 0.f;
        split16(v, Xh0[idx], Xl0[idx]);
    }
    float cReg[4] = {0.f, 0.f, 0.f, 0.f};
    gridg.sync();

    for (int t = 0; t < Tsz; ++t) {
        const f16* XhC = (t & 1) ? Xh1 : Xh0;
        const f16* XlC = (t & 1) ? Xl1 : Xl0;
        f16* XhN = (t & 1) ? Xh0 : Xh1;
        f16* XlN = (t & 1) ? Xl0 : Xl1;

        // ================= phase A: gates + cell =================
        {
            const f16* aSrcH = XhC + (size_t)(r0 + (tid>>2))*SX + aswz;
            const f16* aSrcL = XlC + (size_t)(r0 + (tid>>2))*SX + aswz;
            const f16* bSrcH = Wh + (size_t)ct*2048 + tid*8;
            const f16* bSrcL = Wl + (size_t)ct*2048 + tid*8;
            f32x4 hh[2][2] = {}, hl[2][2] = {}, lh[2][2] = {};

            auto issueLoads = [&](int c) {
                const int buf = c & 3;
                char* dA = smem + buf*8192 + tid*16;
                char* dB = smem + 32768 + buf*8192 + tid*16;
                glds16(aSrcH + c*32, dA);
                glds16(aSrcL + c*32, dA + 4096);
                glds16(bSrcH + (size_t)c*131072, dB);
                glds16(bSrcL + (size_t)c*131072, dB + 4096);
            };
            auto compute = [&](int c) {
                const char* At = smem + (c & 3)*8192;
                const char* Bt = smem + 32768 + (c & 3)*8192;
                f16x8 ah[2], al[2], bh[2], bl[2];
#pragma unroll
                for (int R = 0; R < 2; ++R) {
                    ah[R] = *(const f16x8*)(At + offA[R]);
                    al[R] = *(const f16x8*)(At + 4096 + offA[R]);
                    bh[R] = *(const f16x8*)(Bt + offB[R]);
                    bl[R] = *(const f16x8*)(Bt + 4096 + offB[R]);
                }
#pragma unroll
                for (int R = 0; R < 2; ++R)
#pragma unroll
                    for (int C = 0; C < 2; ++C) {
                        hh[R][C] = MFMA16(ah[R], bh[C], hh[R][C]);
                        hl[R][C] = MFMA16(ah[R], bl[C], hl[R][C]);
                        lh[R][C] = MFMA16(al[R], bh[C], lh[R][C]);
                    }
            };

            issueLoads(0); issueLoads(1); issueLoads(2);
#pragma unroll 1
            for (int c = 0; c < KCH-3; ++c) {
                WAIT_BAR(8);
                issueLoads(c+3);
                compute(c);
            }
            WAIT_BAR(8); compute(KCH-3);
            WAIT_BAR(4); compute(KCH-2);
            WAIT_BAR(0); compute(KCH-1);
            __syncthreads();

            float* gl = (float*)smem;   // 64x64 f32
#pragma unroll
            for (int R = 0; R < 2; ++R)
#pragma unroll
                for (int C = 0; C < 2; ++C) {
                    f32x4 d = hh[R][C] + (hl[R][C] + lh[R][C]) * LOINV;
                    int col = wc*32 + C*16 + (l & 15);
                    int rb = wr*32 + R*16 + ((l >> 4) << 2);
#pragma unroll
                    for (int j = 0; j < 4; ++j) {
                        int r = rb + j;
                        gl[r*64 + (col ^ ((r & 7) << 2))] = d[j];
                    }
                }
            __syncthreads();
#pragma unroll
            for (int q = 0; q < 4; ++q) {
                int s = q*256 + tid;
                int m = s >> 4, u = s & 15;
                f32x4 gt = *(const f32x4*)(gl + m*64 + ((u << 2) ^ ((m & 7) << 2)));
                f32x4 cg4 = *(const f32x4*)(cgp + (size_t)(r0 + m)*4096 + p0 + (u << 2));
                float gi = gt.x + cg4.x, gf = gt.y + cg4.y, gg = gt.z + cg4.z, go = gt.w + cg4.w;
                int ug = ct*16 + u;
                float cO = cReg[q];
                float cN = sigm(gf)*cO + sigm(gi)*tanhf(gg);
                float hN = sigm(go)*tanhf(cN);
                cReg[q] = cN;
                split16(hN, XhN[(size_t)(r0 + m)*SX + 288 + ug],
                            XlN[(size_t)(r0 + m)*SX + 288 + ug]);
            }
        }
        gridg.sync();

        // ================= phase B: proj split-K partials =================
        if (bid < 160) {
            const f16* aH = XhN + (size_t)(prt*64 + (tid>>2))*SX + 288 + pks*128 + aswz;
            const f16* aL = XlN + (size_t)(prt*64 + (tid>>2))*SX + 288 + pks*128 + aswz;
            f32x4 qh[2][2] = {}, ql[2][2] = {}, qlh[2][2] = {};
#pragma unroll
            for (int c = 0; c < 4; ++c) {
                char* base = smem + c*16384;
                size_t bb = ((size_t)((pks*4 + c)*5 + pct))*2048 + tid*8;
                glds16(aH + c*32, base + tid*16);
                glds16(aL + c*32, base + 4096 + tid*16);
                glds16(Lh + bb, base + 8192 + tid*16);
                glds16(Ll + bb, base + 12288 + tid*16);
            }
            auto computeP = [&](int c) {
                const char* At = smem + c*16384;
                const char* Bt = smem + c*16384 + 8192;
                f16x8 ah[2], al[2], bh[2], bl[2];
#pragma unroll
                for (int R = 0; R < 2; ++R) {
                    ah[R] = *(const f16x8*)(At + offA[R]);
                    al[R] = *(const f16x8*)(At + 4096 + offA[R]);
                    bh[R] = *(const f16x8*)(Bt + offB[R]);
                    bl[R] = *(const f16x8*)(Bt + 4096 + offB[R]);
                }
#pragma unroll
                for (int R = 0; R < 2; ++R)
#pragma unroll
                    for (int C = 0; C < 2; ++C) {
                        qh[R][C]  = MFMA16(ah[R], bh[C], qh[R][C]);
                        ql[R][C]  = MFMA16(ah[R], bl[C], ql[R][C]);
                        qlh[R][C] = MFMA16(al[R], bh[C], qlh[R][C]);
                    }
            };
            WAIT_BAR(12); computeP(0);
            WAIT_BAR(8);  computeP(1);
            WAIT_BAR(4);  computeP(2);
            WAIT_BAR(0);  computeP(3);

            float* pout = partial + (size_t)pks*81920;
#pragma unroll
            for (int R = 0; R < 2; ++R)
#pragma unroll
                for (int C = 0; C < 2; ++C) {
                    f32x4 d = qh[R][C] + (ql[R][C] + qlh[R][C]) * LOINV;
                    int col = pct*64 + wc*32 + C*16 + (l & 15);
                    int rb = prt*64 + wr*32 + R*16 + ((l >> 4) << 2);
#pragma unroll
                    for (int j = 0; j < 4; ++j)
                        pout[(size_t)(rb + j)*320 + col] = d[j];
                }
        }
        gridg.sync();

        // ================= phase C: reduce + frame update =================
        for (int idx = gid; idx < 256*288; idx += 65536) {
            int b = idx / 288, f = idx - b*288;
            size_t xoff = (size_t)b*SX + f;
            if (f < Fsz) {
                float v = ((t == 0) ? motions[(size_t)b*TFs + f]
                                    : out[(size_t)b*TFs + (size_t)(t-1)*Fsz + f]) + l2b[f];
#pragma unroll
                for (int ks = 0; ks < 8; ++ks)
                    v += partial[(size_t)ks*81920 + b*320 + f];
                out[(size_t)b*TFs + (size_t)t*Fsz + f] = v;
                split16(v, XhN[xoff], XlN[xoff]);
            } else {
                XhN[xoff] = (f16)0.f;
                XlN[xoff] = (f16)0.f;
            }
        }
        gridg.sync();
    }
}

extern "C" void kernel_launch(void* const* d_in, const int* in_sizes, int n_in,
                              void* d_out_v, int out_size, void* d_ws, size_t ws_size,
                              hipStream_t stream) {
    const float* motions = (const float*)d_in[0];
    const float* temb    = (const float*)d_in[1];
    const float* ltw     = (const float*)d_in[2];   // (512,768)
    const float* ltb     = (const float*)d_in[3];
    const float* l1w     = (const float*)d_in[4];   // (512,263)
    const float* l1b     = (const float*)d_in[5];
    const float* wih     = (const float*)d_in[6];   // (4096,1024)
    const float* whh     = (const float*)d_in[7];   // (4096,1024)
    const float* bih     = (const float*)d_in[8];
    const float* bhh     = (const float*)d_in[9];
    const float* l2w     = (const float*)d_in[10];  // (263,1024)
    const float* l2b     = (const float*)d_in[11];
    float* out = (float*)d_out_v;
    char* ws = (char*)d_ws;
    if (ws_size < (size_t)WS_BYTES) return;

    f16*   WallHi = (f16*)(ws + OFF_WALLHI);
    f16*   WallLo = (f16*)(ws + OFF_WALLLO);
    float* WihT   = (float*)(ws + OFF_WALLHI);    // phase-1 alias
    float* Wcomb  = (float*)(ws + OFF_PART);      // phase-1 alias
    float* part   = (float*)(ws + OFF_PART);
    float* cgj    = (float*)(ws + OFF_XHI0);      // phase-1 alias
    f16*   Xh0p   = (f16*)(ws + OFF_XHI0);
    f16*   Xl0p   = (f16*)(ws + OFF_XLO0);
    f16*   Xh1p   = (f16*)(ws + OFF_XHI1);
    f16*   Xl1p   = (f16*)(ws + OFF_XLO1);
    float* cgp    = (float*)(ws + OFF_CGP);
    f16*   L2h    = (f16*)(ws + OFF_L2PH);
    f16*   L2l    = (f16*)(ws + OFF_L2PL);
    float* lin1t  = (float*)(ws + OFF_LIN1T);
    float* ltwT   = (float*)(ws + OFF_LTWT);
    float* textE  = (float*)(ws + OFF_TEXTE);
    float* biasG  = (float*)(ws + OFF_BIASG);
    float* WcT    = (float*)(ws + OFF_WCT);

    dim3 blk(256);
    // ---- precompute ----
    tpose<<<dim3(32,128), blk, 0, stream>>>(wih, WihT, 4096, 1024);
    tpose<<<dim3(24, 16), blk, 0, stream>>>(ltw, ltwT, 512, 768);
    tpose<<<dim3( 9, 16), blk, 0, stream>>>(l1w, lin1t, 512, 263);
    biasg_k<<<1024, blk, 0, stream>>>(bih, bhh, l1b, wih, biasG);
    nn_gemm<<<dim3( 8, 8), blk, 0, stream>>>(temb, ltwT, ltb, textE, 256, 256, 512, 768);
    nn_gemm<<<dim3(64, 9), blk, 0, stream>>>(lin1t, WihT, nullptr, Wcomb, 288, 263, 4096, 512);
    nn_gemm<<<dim3(64, 8), blk, 0, stream>>>(textE, WihT + (size_t)512*4096, biasG, cgj,
                                             256, 256, 4096, 512);
    tpose<<<dim3(128, 9), blk, 0, stream>>>(Wcomb, WcT, 288, 4096);
    permute_cg<<<4096, blk, 0, stream>>>(cgj, cgp);
    pack_wall<<<dim3(64, 41), blk, 0, stream>>>(WcT, whh, WallHi, WallLo);
    pack_lin2<<<dim3(5, 32), blk, 0, stream>>>(l2w, L2h, L2l);

    // ---- persistent recurrence (cooperative, 1 block/CU) ----
    void* args[] = {
        (void*)&motions, (void*)&l2b, (void*)&out,
        (void*)&WallHi, (void*)&WallLo, (void*)&L2h, (void*)&L2l,
        (void*)&cgp, (void*)&part,
        (void*)&Xh0p, (void*)&Xl0p, (void*)&Xh1p, (void*)&Xl1p
    };
    hipLaunchCooperativeKernel(reinterpret_cast<void*>(kmain),
                               dim3(256), dim3(256), args, 0, stream);
}

// Round 9
// 11460.454 us; speedup vs baseline: 1.9063x; 1.9063x over previous
//
#include <hip/hip_runtime.h>
#include <math.h>

typedef _Float16 f16;
typedef __attribute__((ext_vector_type(8))) _Float16 f16x8;
typedef __attribute__((ext_vector_type(4))) float f32x4;

#define Bsz 256
#define Tsz 196
#define Fsz 263
#define TFs (Tsz*Fsz)   // 51548
#define SX  1312        // X row stride (288 frame-pad + 1024 h)
#define KCH 41
#define LOSC 2048.0f
#define LOINV 0.00048828125f

// ---------------- ws layout (BYTE offsets) ----------------
#define OFF_WALLHI 0u            // 41*64*2048 f16 = 10747904 B
#define OFF_WALLLO 10747904u
#define OFF_PART   21495808u     // f32 partial [64ct][272f][256b] = 17825792 B
#define OFF_CST    39321600u     // c state f32 [256][1024] = 1048576
#define OFF_CGP    40370176u     // constG permuted f32 [256][4096] = 4194304
#define OFF_LPH    44564480u     // lin2 frag-pack hi 64*17*32*8 f16 = 557056 B
#define OFF_LPL    45121536u
#define OFF_XHI0   45678592u     // 671744 each
#define OFF_XLO0   46350336u
#define OFF_XHI1   47022080u
#define OFF_XLO1   47693824u
#define OFF_CTR    48365568u     // ctr[4], ctr2[4]
#define WS_BYTES   48365632u
// precompute-only aliases (all dead before their region is overwritten):
//   WihT  f32 @0 (16.8MB)           dead before pack_wall
//   Wcomb @OFF_PART (4.72MB), cgj @OFF_PART+4718592 (4MB)   dead before loop
//   WcT   @OFF_CST (4.72MB, overlaps CGP region)            dead before permute_cg
//   lin1t/ltwT/textE/biasG @X region                        dead before init_k

__device__ __forceinline__ void glds16(const void* g, void* l) {
    __builtin_amdgcn_global_load_lds(
        (const __attribute__((address_space(1))) void*)g,
        (__attribute__((address_space(3))) void*)l, 16, 0, 0);
}
__device__ __forceinline__ float sigm(float x) { return 1.f / (1.f + expf(-x)); }
__device__ __forceinline__ void split16(float x, f16& hi, f16& lo) {
    hi = (f16)x;
    lo = (f16)((x - (float)hi) * LOSC);
}
#define MFMA16(a,b,c) __builtin_amdgcn_mfma_f32_16x16x32_f16(a,b,c,0,0,0)
#define WAIT_BAR(N) do { \
    asm volatile("s_waitcnt vmcnt(" #N ")" ::: "memory"); \
    __builtin_amdgcn_s_barrier(); \
    __builtin_amdgcn_sched_barrier(0); \
} while (0)

// ---------------- precompute kernels ----------------
__global__ __launch_bounds__(256) void tpose(const float* __restrict__ src,
                                             float* __restrict__ dst, int M, int N) {
    __shared__ float tile[32][33];
    int bx = blockIdx.x, by = blockIdx.y;
    int tx = threadIdx.x & 31, ty = threadIdx.x >> 5;
#pragma unroll
    for (int i = 0; i < 4; ++i) {
        int row = by*32 + ty*4 + i, col = bx*32 + tx;
        tile[ty*4+i][tx] = (row < M && col < N) ? src[(size_t)row*N + col] : 0.f;
    }
    __syncthreads();
#pragma unroll
    for (int i = 0; i < 4; ++i) {
        int row = bx*32 + ty*4 + i, col = by*32 + tx;
        if (row < N && col < M) dst[(size_t)row*M + col] = tile[tx][ty*4+i];
    }
}

__global__ __launch_bounds__(256) void biasg_k(const float* __restrict__ bih,
                                               const float* __restrict__ bhh,
                                               const float* __restrict__ l1b,
                                               const float* __restrict__ wih,
                                               float* __restrict__ bg) {
    int j = blockIdx.x*4 + (threadIdx.x >> 6);
    int l = threadIdx.x & 63;
    const float* wr = wih + (size_t)j*1024 + l*8;
    const float* lb = l1b + l*8;
    float s = 0.f;
#pragma unroll
    for (int e = 0; e < 8; ++e) s += lb[e] * wr[e];
#pragma unroll
    for (int off = 32; off; off >>= 1) s += __shfl_down(s, off, 64);
    if (l == 0) bg[j] = bih[j] + bhh[j] + s;
}

__global__ __launch_bounds__(256) void nn_gemm(const float* __restrict__ A,
                                               const float* __restrict__ B,
                                               const float* __restrict__ bias,
                                               float* __restrict__ C,
                                               int M, int MA, int N, int K) {
    __shared__ float As[32][33];
    __shared__ float Bs[32][64];
    int tid = threadIdx.x;
    int r0 = blockIdx.y*32, c0 = blockIdx.x*64;
    int tr = tid >> 4, tc = tid & 15;
    float acc[2][4] = {};
    for (int k0 = 0; k0 < K; k0 += 32) {
        int m = tid >> 3, kb = (tid & 7)*4;
        int row = r0 + m;
#pragma unroll
        for (int i = 0; i < 4; ++i)
            As[m][kb+i] = (row < MA) ? A[(size_t)row*K + k0 + kb + i] : 0.f;
#pragma unroll
        for (int i = 0; i < 8; ++i) {
            int fi = i*256 + tid, kk = fi >> 6, cc = fi & 63;
            Bs[kk][cc] = B[(size_t)(k0+kk)*N + c0 + cc];
        }
        __syncthreads();
#pragma unroll
        for (int k = 0; k < 32; ++k) {
            float a0 = As[2*tr][k], a1 = As[2*tr+1][k];
            float b0 = Bs[k][4*tc], b1 = Bs[k][4*tc+1], b2 = Bs[k][4*tc+2], b3 = Bs[k][4*tc+3];
            acc[0][0]+=a0*b0; acc[0][1]+=a0*b1; acc[0][2]+=a0*b2; acc[0][3]+=a0*b3;
            acc[1][0]+=a1*b0; acc[1][1]+=a1*b1; acc[1][2]+=a1*b2; acc[1][3]+=a1*b3;
        }
        __syncthreads();
    }
#pragma unroll
    for (int i = 0; i < 2; ++i) {
        int row = r0 + 2*tr + i;
        if (row < M)
#pragma unroll
            for (int j = 0; j < 4; ++j) {
                int col = c0 + 4*tc + j;
                C[(size_t)row*N + col] = acc[i][j] + (bias ? bias[col] : 0.f);
            }
    }
}

__global__ __launch_bounds__(256) void pack_wall(const float* __restrict__ WcT,
                                                 const float* __restrict__ whh,
                                                 f16* __restrict__ Wh,
                                                 f16* __restrict__ Wl) {
    int q = threadIdx.x;
    int ct = blockIdx.x, kc = blockIdx.y;
    int k = kc*32 + (((q&3) ^ ((q>>3)&3)) << 3);
    int p = ct*64 + (q>>2);
    int j = (p&3)*1024 + (p>>2);
    size_t ob = ((size_t)(kc*64 + ct)*256 + q)*8;
#pragma unroll
    for (int e = 0; e < 8; ++e) {
        int kk = k + e;
        float v = (kk < 288) ? WcT[(size_t)j*288 + kk]
                             : whh[(size_t)j*1024 + (kk - 288)];
        split16(v, Wh[ob+e], Wl[ob+e]);
    }
}

// lin2 frag pack: B-frag image for proj: lane l<32 holds B[k=(l>>4)*8+e][col f]
__global__ __launch_bounds__(256) void pack_lp(const float* __restrict__ l2w,
                                               f16* __restrict__ LpH,
                                               f16* __restrict__ LpL) {
    int ctb = blockIdx.x, C = blockIdx.y;   // 64, 17
    int l = threadIdx.x & 31, e = threadIdx.x >> 5;  // e 0..7
    int f = C*16 + (l & 15);
    int u = ctb*16 + (l >> 4)*8 + e;
    float v = (f < Fsz) ? l2w[(size_t)f*1024 + u] : 0.f;
    size_t o = ((size_t)(ctb*17 + C)*32 + l)*8 + e;
    split16(v, LpH[o], LpL[o]);
}

__global__ __launch_bounds__(256) void permute_cg(const float* __restrict__ cj,
                                                  float* __restrict__ cp) {
    int idx = blockIdx.x*256 + threadIdx.x;
    int b = idx >> 12, p = idx & 4095;
    cp[idx] = cj[(b << 12) + ((p & 3) << 10) + (p >> 2)];
}

__global__ __launch_bounds__(256) void init_k(const float* __restrict__ motions,
                                              f16* __restrict__ Xh0,
                                              f16* __restrict__ Xl0,
                                              float* __restrict__ cSt,
                                              unsigned* __restrict__ ctr) {
    int idx = blockIdx.x*256 + threadIdx.x;
    if (idx < 256*SX) {
        int b = idx / SX, k = idx - b*SX;
        float v = (k < Fsz) ? motions[(size_t)b*TFs + k] : 0.f;
        split16(v, Xh0[idx], Xl0[idx]);
    } else if (idx < 256*SX + 262144) {
        cSt[idx - 256*SX] = 0.f;
    } else if (idx < 256*SX + 262144 + 8) {
        ctr[idx - 256*SX - 262144] = 0u;
    }
}

// ---------------- the per-step kernel: gates GEMM + cell + proj + reduce ----------------
// grid (64 ct, 4 rt) = 256 blocks (1/CU, all co-resident), 256 threads.
__global__ __launch_bounds__(256) void kstep(
        const f16* __restrict__ Xh, const f16* __restrict__ Xl,
        const f16* __restrict__ Wh, const f16* __restrict__ Wl,
        const float* __restrict__ cgp, float* __restrict__ cSt,
        f16* __restrict__ XhN, f16* __restrict__ XlN,
        const f16* __restrict__ LpH, const f16* __restrict__ LpL,
        float* __restrict__ part,
        const float* __restrict__ fprev, const float* __restrict__ l2b,
        float* __restrict__ outT, unsigned* __restrict__ ctr)
{
    __shared__ __attribute__((aligned(16))) char smem[65536];   // 8 B-bufs x 8KB
    const int tid = threadIdx.x;
    const int ct = blockIdx.x, rt = blockIdx.y;
    const int r0 = rt*64, p0 = ct*64;
    const int l = tid & 63;
    const int wr = (tid >> 7) & 1, wc = (tid >> 6) & 1;

    const f16* bSrcH = Wh + (size_t)ct*2048 + tid*8;
    const f16* bSrcL = Wl + (size_t)ct*2048 + tid*8;
    const f16* aBaseH = Xh + (size_t)(r0 + wr*32 + (l & 15))*SX + (l >> 4)*8;
    const f16* aBaseL = Xl + (size_t)(r0 + wr*32 + (l & 15))*SX + (l >> 4)*8;

    int offB[2];
#pragma unroll
    for (int C = 0; C < 2; ++C) {
        int g = l >> 4;
        int col = wc*32 + C*16 + (l & 15);
        offB[C] = col*64 + ((g ^ ((col>>1)&3)) & 3)*16;
    }
    f32x4 hh[2][2] = {}, hl[2][2] = {}, lh[2][2] = {};
    f16x8 aH[3][2], aL[3][2];

#define ISSUE_B(cc_) do { int cc = (cc_) > 40 ? 40 : (cc_); \
    char* dB = smem + (cc & 7)*8192 + tid*16; \
    glds16(bSrcH + (size_t)cc*131072, dB); \
    glds16(bSrcL + (size_t)cc*131072, dB + 4096); } while(0)
#define ISSUE_A(c_, s_) do { \
    const f16* pH = aBaseH + (c_)*32; const f16* pL = aBaseL + (c_)*32; \
    aH[s_][0] = *(const f16x8*)pH; aH[s_][1] = *(const f16x8*)(pH + 16*SX); \
    aL[s_][0] = *(const f16x8*)pL; aL[s_][1] = *(const f16x8*)(pL + 16*SX); } while(0)
#define COMPUTE(c_, s_) do { \
    const char* Bt = smem + ((c_) & 7)*8192; \
    f16x8 bh0 = *(const f16x8*)(Bt + offB[0]); \
    f16x8 bh1 = *(const f16x8*)(Bt + offB[1]); \
    f16x8 bl0 = *(const f16x8*)(Bt + 4096 + offB[0]); \
    f16x8 bl1 = *(const f16x8*)(Bt + 4096 + offB[1]); \
    hh[0][0] = MFMA16(aH[s_][0], bh0, hh[0][0]); \
    hh[0][1] = MFMA16(aH[s_][0], bh1, hh[0][1]); \
    hh[1][0] = MFMA16(aH[s_][1], bh0, hh[1][0]); \
    hh[1][1] = MFMA16(aH[s_][1], bh1, hh[1][1]); \
    hl[0][0] = MFMA16(aH[s_][0], bl0, hl[0][0]); \
    hl[0][1] = MFMA16(aH[s_][0], bl1, hl[0][1]); \
    hl[1][0] = MFMA16(aH[s_][1], bl0, hl[1][0]); \
    hl[1][1] = MFMA16(aH[s_][1], bl1, hl[1][1]); \
    lh[0][0] = MFMA16(aL[s_][0], bh0, lh[0][0]); \
    lh[0][1] = MFMA16(aL[s_][0], bh1, lh[0][1]); \
    lh[1][0] = MFMA16(aL[s_][1], bh0, lh[1][0]); \
    lh[1][1] = MFMA16(aL[s_][1], bh1, lh[1][1]); } while(0)
#define KSTEP3(c_, sc_, sn_) do { \
    WAIT_BAR(6); \
    ISSUE_B((c_) + 6); \
    __builtin_amdgcn_sched_barrier(0); \
    ISSUE_A((c_) + 2, sn_); \
    __builtin_amdgcn_sched_barrier(0); \
    COMPUTE(c_, sc_); } while(0)

    // prologue: B0..B4, A0, B5, A1  (first wait vmcnt(6) leaves [B5,A1] in flight)
    ISSUE_B(0); ISSUE_B(1); ISSUE_B(2); ISSUE_B(3); ISSUE_B(4);
    __builtin_amdgcn_sched_barrier(0);
    ISSUE_A(0, 0);
    __builtin_amdgcn_sched_barrier(0);
    ISSUE_B(5);
    __builtin_amdgcn_sched_barrier(0);
    ISSUE_A(1, 1);
    __builtin_amdgcn_sched_barrier(0);

#pragma unroll 1
    for (int cb = 0; cb < 13; ++cb) {
        int c = cb*3;
        KSTEP3(c,   0, 2);
        KSTEP3(c+1, 1, 0);
        KSTEP3(c+2, 2, 1);
    }
    WAIT_BAR(6); COMPUTE(39, 0);
    WAIT_BAR(0); COMPUTE(40, 1);
    __syncthreads();

    // ---- gates -> LDS (swizzled) ----
    float* gl = (float*)smem;   // 64x64 f32
#pragma unroll
    for (int R = 0; R < 2; ++R)
#pragma unroll
        for (int C = 0; C < 2; ++C) {
            f32x4 d = hh[R][C] + (hl[R][C] + lh[R][C]) * LOINV;
            int col = wc*32 + C*16 + (l & 15);
            int rb = wr*32 + R*16 + ((l >> 4) << 2);
#pragma unroll
            for (int j = 0; j < 4; ++j) {
                int r = rb + j;
                gl[r*64 + (col ^ ((r & 7) << 2))] = d[j];
            }
        }
    __syncthreads();

    // ---- cell update; h -> global limbs + LDS frag buffer ----
    f16* hl16h = (f16*)(smem + 16384);   // [64][16]
    f16* hl16l = (f16*)(smem + 18432);
#pragma unroll
    for (int q = 0; q < 4; ++q) {
        int s = q*256 + tid;
        int m = s >> 4, u = s & 15;
        f32x4 gt = *(const f32x4*)(gl + m*64 + ((u << 2) ^ ((m & 7) << 2)));
        f32x4 cg4 = *(const f32x4*)(cgp + (size_t)(r0 + m)*4096 + p0 + (u << 2));
        float gi = gt.x + cg4.x, gf = gt.y + cg4.y, gg = gt.z + cg4.z, go = gt.w + cg4.w;
        int ug = ct*16 + u;
        int ci = (r0 + m)*1024 + ug;
        float cO = cSt[ci];
        float cN = sigm(gf)*cO + sigm(gi)*tanhf(gg);
        float hN = sigm(go)*tanhf(cN);
        cSt[ci] = cN;
        f16 hi, lo;
        split16(hN, hi, lo);
        XhN[(size_t)(r0 + m)*SX + 288 + ug] = hi;
        XlN[(size_t)(r0 + m)*SX + 288 + ug] = lo;
        hl16h[m*16 + u] = hi;
        hl16l[m*16 + u] = lo;
    }
    __syncthreads();

    // ---- proj partial (f32): h-slice(64x16) @ lin2[ct-slice](16x272), K padded to 32 ----
    {
        f16x8 pah[2], pal[2];
#pragma unroll
        for (int R = 0; R < 2; ++R) {
            if (l < 32) {
                int hoff = (wr*32 + R*16 + (l & 15))*16 + (l >> 4)*8;
                pah[R] = *(const f16x8*)(hl16h + hoff);
                pal[R] = *(const f16x8*)(hl16l + hoff);
            } else { pah[R] = (f16)0; pal[R] = (f16)0; }
        }
#pragma unroll 2
        for (int C0 = 0; C0 < 9; ++C0) {
            int C = wc*9 + C0;
            if (C >= 17) continue;
            f16x8 pbh = (f16)0, pbl = (f16)0;
            if (l < 32) {
                size_t bo = ((size_t)(ct*17 + C)*32 + l)*8;
                pbh = *(const f16x8*)(LpH + bo);
                pbl = *(const f16x8*)(LpL + bo);
            }
#pragma unroll
            for (int R = 0; R < 2; ++R) {
                f32x4 vh = {}, vm = {}, vl2 = {};
                vh  = MFMA16(pah[R], pbh, vh);
                vm  = MFMA16(pah[R], pbl, vm);
                vl2 = MFMA16(pal[R], pbh, vl2);
                f32x4 d = vh + (vm + vl2) * LOINV;
                int fcol = C*16 + (l & 15);
                int row = rt*64 + wr*32 + R*16 + ((l >> 4) << 2);
                *(f32x4*)(part + ((size_t)(ct*272 + fcol))*256 + row) = d;
            }
        }
    }

    // ---- release -> counter -> spin (relaxed) -> acquire ----
    __syncthreads();   // drains each wave's stores (vmcnt 0) before barrier
    if (tid == 0) {
        __hip_atomic_fetch_add(&ctr[rt], 1u, __ATOMIC_RELEASE, __HIP_MEMORY_SCOPE_AGENT);
        while (__hip_atomic_load(&ctr[rt], __ATOMIC_RELAXED, __HIP_MEMORY_SCOPE_AGENT) < 64u)
            __builtin_amdgcn_s_sleep(8);
        __builtin_amdgcn_fence(__ATOMIC_ACQUIRE, "agent");
    }
    __syncthreads();

    // ---- distributed reduce: this block sums cols ct*5..+5 for rows rt*64..+64 ----
    for (int e = tid; e < 320; e += 256) {
        int f = ct*5 + (e >> 6);
        int b = rt*64 + (e & 63);
        if (f < 288) {
            if (f < Fsz) {
                float s = 0.f;
                const float* pp = part + (size_t)f*256 + b;
#pragma unroll 8
                for (int kct = 0; kct < 64; ++kct)
                    s += pp[(size_t)kct*69632];
                float v = fprev[(size_t)b*TFs + f] + l2b[f] + s;
                outT[(size_t)b*TFs + f] = v;
                split16(v, XhN[(size_t)b*SX + f], XlN[(size_t)b*SX + f]);
            } else {
                XhN[(size_t)b*SX + f] = (f16)0.f;
                XlN[(size_t)b*SX + f] = (f16)0.f;
            }
        }
    }

    // ---- counter reset by last finisher ----
    __syncthreads();
    if (tid == 0) {
        unsigned o2 = __hip_atomic_fetch_add(&ctr[4 + rt], 1u, __ATOMIC_RELAXED,
                                             __HIP_MEMORY_SCOPE_AGENT);
        if (o2 == 63u) {
            __hip_atomic_store(&ctr[rt], 0u, __ATOMIC_RELAXED, __HIP_MEMORY_SCOPE_AGENT);
            __hip_atomic_store(&ctr[4 + rt], 0u, __ATOMIC_RELAXED, __HIP_MEMORY_SCOPE_AGENT);
        }
    }
#undef ISSUE_B
#undef ISSUE_A
#undef COMPUTE
#undef KSTEP3
}

extern "C" void kernel_launch(void* const* d_in, const int* in_sizes, int n_in,
                              void* d_out_v, int out_size, void* d_ws, size_t ws_size,
                              hipStream_t stream) {
    const float* motions = (const float*)d_in[0];
    const float* temb    = (const float*)d_in[1];
    const float* ltw     = (const float*)d_in[2];   // (512,768)
    const float* ltb     = (const float*)d_in[3];
    const float* l1w     = (const float*)d_in[4];   // (512,263)
    const float* l1b     = (const float*)d_in[5];
    const float* wih     = (const float*)d_in[6];   // (4096,1024)
    const float* whh     = (const float*)d_in[7];   // (4096,1024)
    const float* bih     = (const float*)d_in[8];
    const float* bhh     = (const float*)d_in[9];
    const float* l2w     = (const float*)d_in[10];  // (263,1024)
    const float* l2b     = (const float*)d_in[11];
    float* out = (float*)d_out_v;
    char* ws = (char*)d_ws;
    if (ws_size < (size_t)WS_BYTES) return;

    f16*      WallHi = (f16*)(ws + OFF_WALLHI);
    f16*      WallLo = (f16*)(ws + OFF_WALLLO);
    float*    partP  = (float*)(ws + OFF_PART);
    float*    cSt    = (float*)(ws + OFF_CST);
    float*    cgp    = (float*)(ws + OFF_CGP);
    f16*      LpH    = (f16*)(ws + OFF_LPH);
    f16*      LpL    = (f16*)(ws + OFF_LPL);
    f16*      XhB[2] = { (f16*)(ws + OFF_XHI0), (f16*)(ws + OFF_XHI1) };
    f16*      XlB[2] = { (f16*)(ws + OFF_XLO0), (f16*)(ws + OFF_XLO1) };
    unsigned* ctr    = (unsigned*)(ws + OFF_CTR);
    // precompute aliases
    float* WihT  = (float*)(ws + 0);
    float* Wcomb = (float*)(ws + OFF_PART);
    float* cgj   = (float*)(ws + OFF_PART + 4718592u);
    float* WcT   = (float*)(ws + OFF_CST);
    float* lin1t = (float*)(ws + OFF_XHI0);
    float* ltwT  = (float*)(ws + OFF_XHI0 + 538624u);
    float* textE = (float*)(ws + OFF_XHI0 + 538624u + 1572864u);
    float* biasG = (float*)(ws + OFF_XHI0 + 538624u + 1572864u + 524288u);

    dim3 blk(256);
    tpose<<<dim3(32,128), blk, 0, stream>>>(wih, WihT, 4096, 1024);
    tpose<<<dim3(24, 16), blk, 0, stream>>>(ltw, ltwT, 512, 768);
    tpose<<<dim3( 9, 16), blk, 0, stream>>>(l1w, lin1t, 512, 263);
    biasg_k<<<1024, blk, 0, stream>>>(bih, bhh, l1b, wih, biasG);
    nn_gemm<<<dim3( 8, 8), blk, 0, stream>>>(temb, ltwT, ltb, textE, 256, 256, 512, 768);
    nn_gemm<<<dim3(64, 9), blk, 0, stream>>>(lin1t, WihT, nullptr, Wcomb, 288, 263, 4096, 512);
    nn_gemm<<<dim3(64, 8), blk, 0, stream>>>(textE, WihT + (size_t)512*4096, biasG, cgj,
                                             256, 256, 4096, 512);
    tpose<<<dim3(128, 9), blk, 0, stream>>>(Wcomb, WcT, 288, 4096);
    pack_wall<<<dim3(64, 41), blk, 0, stream>>>(WcT, whh, WallHi, WallLo);
    permute_cg<<<4096, blk, 0, stream>>>(cgj, cgp);
    pack_lp<<<dim3(64, 17), blk, 0, stream>>>(l2w, LpH, LpL);
    init_k<<<2337, blk, 0, stream>>>(motions, XhB[0], XlB[0], cSt, ctr);

    for (int t = 0; t < Tsz; ++t) {
        f16* Xhc = XhB[t & 1],      *Xlc = XlB[t & 1];
        f16* Xhn = XhB[(t+1) & 1],  *Xln = XlB[(t+1) & 1];
        const float* fprev = (t == 0) ? motions : (out + (size_t)(t-1)*Fsz);
        kstep<<<dim3(64, 4), blk, 0, stream>>>(Xhc, Xlc, WallHi, WallLo, cgp, cSt,
                                               Xhn, Xln, LpH, LpL, partP,
                                               fprev, l2b, out + (size_t)t*Fsz, ctr);
    }
}

// Round 10
// 7680.398 us; speedup vs baseline: 2.8445x; 1.4922x over previous
//
#include <hip/hip_runtime.h>
#include <math.h>

typedef _Float16 f16;
typedef __attribute__((ext_vector_type(8))) _Float16 f16x8;
typedef __attribute__((ext_vector_type(4))) float f32x4;

#define Bsz 256
#define Tsz 196
#define Fsz 263
#define TFs (Tsz*Fsz)   // 51548
#define SX  1312        // X row stride (288 frame-pad + 1024 h)
#define KCH 41
#define LOSC 2048.0f
#define LOINV 0.00048828125f

// ---------------- ws layout (BYTE offsets) ----------------
#define OFF_WPK    0u            // packed W [41][128][2][32][32] f16 = 21495808 B
#define OFF_CST    21495808u     // c state f32 [256][1024] = 1048576
#define OFF_CGP    22544384u     // constG permuted f32 [256][4096] = 4194304
#define OFF_PROJ   26738688u     // proj f32 [8][256][320] = 2621440
#define OFF_L2PH   29360128u     // lin2 pack hi [32][5][2048] f16 = 655360
#define OFF_L2PL   30015488u
#define OFF_XHI0   30670848u     // 671744 each
#define OFF_XLO0   31342592u
#define OFF_XHI1   32014336u
#define OFF_XLO1   32686080u
#define OFF_WCOMB  33357824u     // scratch: 4718592 -> 38076416
#define OFF_CGJ    38076416u     // scratch: 4194304 -> 42270720
#define OFF_WCT    42270720u     // scratch: 4718592 -> 46989312
#define WS_BYTES   46989312u
// small precompute scratch (dead before the region's real user runs):
//   lin1t @OFF_PROJ (538624), biasG @OFF_PROJ+538624 (16384)
//   ltwT  @OFF_XHI0 (1572864, spans X0/X1 region, dead before init_k)
//   textE @OFF_XLO1 (524288, dead before init_k)

__device__ __forceinline__ void glds16(const void* g, void* l) {
    __builtin_amdgcn_global_load_lds(
        (const __attribute__((address_space(1))) void*)g,
        (__attribute__((address_space(3))) void*)l, 16, 0, 0);
}
__device__ __forceinline__ float sigm(float x) { return 1.f / (1.f + expf(-x)); }
__device__ __forceinline__ void split16(float x, f16& hi, f16& lo) {
    hi = (f16)x;
    lo = (f16)((x - (float)hi) * LOSC);
}
#define MFMA16(a,b,c) __builtin_amdgcn_mfma_f32_16x16x32_f16(a,b,c,0,0,0)
#define WAIT_BAR(N) do { \
    asm volatile("s_waitcnt vmcnt(" #N ")" ::: "memory"); \
    __builtin_amdgcn_s_barrier(); \
    __builtin_amdgcn_sched_barrier(0); \
} while (0)

// ---------------- precompute kernels ----------------
__global__ __launch_bounds__(256) void tpose(const float* __restrict__ src,
                                             float* __restrict__ dst, int M, int N) {
    __shared__ float tile[32][33];
    int bx = blockIdx.x, by = blockIdx.y;
    int tx = threadIdx.x & 31, ty = threadIdx.x >> 5;
#pragma unroll
    for (int i = 0; i < 4; ++i) {
        int row = by*32 + ty*4 + i, col = bx*32 + tx;
        tile[ty*4+i][tx] = (row < M && col < N) ? src[(size_t)row*N + col] : 0.f;
    }
    __syncthreads();
#pragma unroll
    for (int i = 0; i < 4; ++i) {
        int row = bx*32 + ty*4 + i, col = by*32 + tx;
        if (row < N && col < M) dst[(size_t)row*M + col] = tile[tx][ty*4+i];
    }
}

__global__ __launch_bounds__(256) void biasg_k(const float* __restrict__ bih,
                                               const float* __restrict__ bhh,
                                               const float* __restrict__ l1b,
                                               const float* __restrict__ wih,
                                               float* __restrict__ bg) {
    int j = blockIdx.x*4 + (threadIdx.x >> 6);
    int l = threadIdx.x & 63;
    const float* wr = wih + (size_t)j*1024 + l*8;
    const float* lb = l1b + l*8;
    float s = 0.f;
#pragma unroll
    for (int e = 0; e < 8; ++e) s += lb[e] * wr[e];
#pragma unroll
    for (int off = 32; off; off >>= 1) s += __shfl_down(s, off, 64);
    if (l == 0) bg[j] = bih[j] + bhh[j] + s;
}

__global__ __launch_bounds__(256) void nn_gemm(const float* __restrict__ A,
                                               const float* __restrict__ B,
                                               const float* __restrict__ bias,
                                               float* __restrict__ C,
                                               int M, int MA, int N, int K) {
    __shared__ float As[32][33];
    __shared__ float Bs[32][64];
    int tid = threadIdx.x;
    int r0 = blockIdx.y*32, c0 = blockIdx.x*64;
    int tr = tid >> 4, tc = tid & 15;
    float acc[2][4] = {};
    for (int k0 = 0; k0 < K; k0 += 32) {
        int m = tid >> 3, kb = (tid & 7)*4;
        int row = r0 + m;
#pragma unroll
        for (int i = 0; i < 4; ++i)
            As[m][kb+i] = (row < MA) ? A[(size_t)row*K + k0 + kb + i] : 0.f;
#pragma unroll
        for (int i = 0; i < 8; ++i) {
            int fi = i*256 + tid, kk = fi >> 6, cc = fi & 63;
            Bs[kk][cc] = B[(size_t)(k0+kk)*N + c0 + cc];
        }
        __syncthreads();
#pragma unroll
        for (int k = 0; k < 32; ++k) {
            float a0 = As[2*tr][k], a1 = As[2*tr+1][k];
            float b0 = Bs[k][4*tc], b1 = Bs[k][4*tc+1], b2 = Bs[k][4*tc+2], b3 = Bs[k][4*tc+3];
            acc[0][0]+=a0*b0; acc[0][1]+=a0*b1; acc[0][2]+=a0*b2; acc[0][3]+=a0*b3;
            acc[1][0]+=a1*b0; acc[1][1]+=a1*b1; acc[1][2]+=a1*b2; acc[1][3]+=a1*b3;
        }
        __syncthreads();
    }
#pragma unroll
    for (int i = 0; i < 2; ++i) {
        int row = r0 + 2*tr + i;
        if (row < M)
#pragma unroll
            for (int j = 0; j < 4; ++j) {
                int col = c0 + 4*tc + j;
                C[(size_t)row*N + col] = acc[i][j] + (bias ? bias[col] : 0.f);
            }
    }
}

// pack W into [kc][ct2=128][limb=2][col=32][kslots] f16, kslot s holds source
// kgroup s ^ ((col>>1)&3)  (matches compute-side XOR read)
__global__ __launch_bounds__(256) void pack_w(const float* __restrict__ WcT,
                                              const float* __restrict__ whh,
                                              f16* __restrict__ W) {
    int tid = threadIdx.x;
    int ct2 = blockIdx.x, kc = blockIdx.y;
    int limb = tid >> 7;
    int col  = (tid >> 2) & 31;
    int s    = tid & 3;
    int g    = s ^ ((col >> 1) & 3);
    int p    = ct2*32 + col;
    int j    = (p & 3)*1024 + (p >> 2);
    size_t ob = ((size_t)kc*128 + ct2)*2048 + tid*8;
#pragma unroll
    for (int e = 0; e < 8; ++e) {
        int k = kc*32 + g*8 + e;
        float v = (k < 288) ? WcT[(size_t)j*288 + k]
                            : whh[(size_t)j*1024 + (k - 288)];
        f16 hi, lo;
        split16(v, hi, lo);
        W[ob + e] = limb ? lo : hi;
    }
}

// lin2 pack (round-6 layout): chunks [kc 0..31][ct 0..4] of 2048 f16 (64 cols x 32 k)
__global__ __launch_bounds__(256) void pack_lin2(const float* __restrict__ l2w,
                                                 f16* __restrict__ Lh,
                                                 f16* __restrict__ Ll) {
    int q = threadIdx.x;
    int ct = blockIdx.x, kc = blockIdx.y;   // ct<5, kc<32
    int k = kc*32 + (((q&3) ^ ((q>>3)&3)) << 3);
    int f = ct*64 + (q>>2);
    size_t ob = ((size_t)(kc*5 + ct)*256 + q)*8;
#pragma unroll
    for (int e = 0; e < 8; ++e) {
        float v = (f < Fsz) ? l2w[(size_t)f*1024 + k + e] : 0.f;
        split16(v, Lh[ob+e], Ll[ob+e]);
    }
}

__global__ __launch_bounds__(256) void permute_cg(const float* __restrict__ cj,
                                                  float* __restrict__ cp) {
    int idx = blockIdx.x*256 + threadIdx.x;
    int b = idx >> 12, p = idx & 4095;
    cp[idx] = cj[(b << 12) + ((p & 3) << 10) + (p >> 2)];
}

__global__ __launch_bounds__(256) void init_k(const float* __restrict__ motions,
                                              f16* __restrict__ Xh0,
                                              f16* __restrict__ Xl0,
                                              float* __restrict__ cSt) {
    int idx = blockIdx.x*256 + threadIdx.x;
    if (idx < 256*SX) {
        int b = idx / SX, k = idx - b*SX;
        float v = (k < Fsz) ? motions[(size_t)b*TFs + k] : 0.f;
        split16(v, Xh0[idx], Xl0[idx]);
    } else if (idx < 256*SX + 262144) {
        cSt[idx - 256*SX] = 0.f;
    }
}

// ---------------- k1: gates GEMM + cell update ----------------
// grid (128 ct2, 4 rt) = 512 blocks (2/CU), 256 thr. Block tile 64 r x 32 p.
// A: reg prefetch depth-3 (4 slots); B: glds, 8 bufs, depth-6. 5 vmem ops/iter,
// WAIT_BAR(9) -> both A(c) and B(c) get 3 iterations of latency cover.
__global__ __launch_bounds__(256, 2) void k1_gates(
        const f16* __restrict__ Xh, const f16* __restrict__ Xl,
        const f16* __restrict__ Wpk,
        const float* __restrict__ cgp, float* __restrict__ cSt,
        f16* __restrict__ XhN, f16* __restrict__ XlN)
{
    __shared__ __attribute__((aligned(16))) char smem[32768];   // 8 B-bufs x 4KB
    const int tid = threadIdx.x;
    const int ct2 = blockIdx.x, rt = blockIdx.y;
    const int r0 = rt*64, p0 = ct2*32;
    const int l = tid & 63;
    const int wr = (tid >> 7) & 1, wc = (tid >> 6) & 1;

    const f16* bSrc  = Wpk + (size_t)ct2*2048 + tid*8;
    const f16* aBaseH = Xh + (size_t)(r0 + wr*32 + (l & 15))*SX + (l >> 4)*8;
    const f16* aBaseL = Xl + (size_t)(r0 + wr*32 + (l & 15))*SX + (l >> 4)*8;

    const int colB = wc*16 + (l & 15);
    const int offB = colB*64 + ((((l >> 4) ^ ((colB >> 1) & 3)) & 3)*16);

    f32x4 hh[2] = {}, hl[2] = {}, lh[2] = {};
    f16x8 aH[4][2], aL[4][2];

#define ISSUE_B(cc_) do { int cc = (cc_) > 40 ? 40 : (cc_); \
    glds16(bSrc + (size_t)cc*262144, smem + (cc & 7)*4096 + tid*16); } while(0)
#define ISSUE_A(c_, s_) do { int ca = (c_) > 40 ? 40 : (c_); \
    const f16* pH = aBaseH + ca*32; const f16* pL = aBaseL + ca*32; \
    aH[s_][0] = *(const f16x8*)pH; aH[s_][1] = *(const f16x8*)(pH + 16*SX); \
    aL[s_][0] = *(const f16x8*)pL; aL[s_][1] = *(const f16x8*)(pL + 16*SX); } while(0)
#define COMPUTE(c_, s_) do { \
    const char* Bt = smem + ((c_) & 7)*4096; \
    f16x8 bh = *(const f16x8*)(Bt + offB); \
    f16x8 bl = *(const f16x8*)(Bt + 2048 + offB); \
    hh[0] = MFMA16(aH[s_][0], bh, hh[0]); \
    hh[1] = MFMA16(aH[s_][1], bh, hh[1]); \
    hl[0] = MFMA16(aH[s_][0], bl, hl[0]); \
    hl[1] = MFMA16(aH[s_][1], bl, hl[1]); \
    lh[0] = MFMA16(aL[s_][0], bh, lh[0]); \
    lh[1] = MFMA16(aL[s_][1], bh, lh[1]); } while(0)
#define STEP(c_, s_) do { \
    WAIT_BAR(9); \
    ISSUE_A((c_) + 3, ((s_) + 3) & 3); \
    __builtin_amdgcn_sched_barrier(0); \
    ISSUE_B((c_) + 6); \
    __builtin_amdgcn_sched_barrier(0); \
    COMPUTE(c_, s_); } while(0)

    // prologue: A0,B0,A1,B1,A2,B2,B3,B4,B5  (newest-9 at first wait = B5..B2,A2,B1)
    ISSUE_A(0, 0); ISSUE_B(0);
    __builtin_amdgcn_sched_barrier(0);
    ISSUE_A(1, 1); ISSUE_B(1);
    __builtin_amdgcn_sched_barrier(0);
    ISSUE_A(2, 2); ISSUE_B(2);
    __builtin_amdgcn_sched_barrier(0);
    ISSUE_B(3); ISSUE_B(4); ISSUE_B(5);
    __builtin_amdgcn_sched_barrier(0);

#pragma unroll 1
    for (int cb = 0; cb < 10; ++cb) {
        int c = cb*4;
        STEP(c,   0);
        STEP(c+1, 1);
        STEP(c+2, 2);
        STEP(c+3, 3);
    }
    STEP(40, 0);
    __syncthreads();

    // ---- D -> LDS (quad-swizzled) ----
    float* gl = (float*)smem;   // 64 x 32 f32 = 8KB
#pragma unroll
    for (int R = 0; R < 2; ++R) {
        f32x4 d = hh[R] + (hl[R] + lh[R]) * LOINV;
        int col = wc*16 + (l & 15);
        int rb = wr*32 + R*16 + ((l >> 4) << 2);
#pragma unroll
        for (int j = 0; j < 4; ++j) {
            int r = rb + j;
            gl[r*32 + (col ^ ((r & 7) << 2))] = d[j];
        }
    }
    __syncthreads();

    // ---- cell update: 64 rows x 8 units per block ----
#pragma unroll
    for (int q = 0; q < 2; ++q) {
        int s = q*256 + tid;
        int m = s >> 3, uu = s & 7;
        f32x4 gt = *(const f32x4*)(gl + m*32 + ((uu << 2) ^ ((m & 7) << 2)));
        f32x4 cg4 = *(const f32x4*)(cgp + (size_t)(r0 + m)*4096 + p0 + (uu << 2));
        float gi = gt.x + cg4.x, gf = gt.y + cg4.y, gg = gt.z + cg4.z, go = gt.w + cg4.w;
        int ug = ct2*8 + uu;
        int ci = (r0 + m)*1024 + ug;
        float cO = cSt[ci];
        float cN = sigm(gf)*cO + sigm(gi)*tanhf(gg);
        float hN = sigm(go)*tanhf(cN);
        cSt[ci] = cN;
        split16(hN, XhN[(size_t)(r0 + m)*SX + 288 + ug],
                    XlN[(size_t)(r0 + m)*SX + 288 + ug]);
    }
#undef ISSUE_B
#undef ISSUE_A
#undef COMPUTE
#undef STEP
}

// ---------------- k3: out-projection, split-K x 8, 4 chunks each ----------------
// grid (5 ct, 4 rt, 8 ks): proj[ks][256][320] = h(256 x 128-slice) @ lin2pack
__global__ __launch_bounds__(256) void k3_proj(
        const f16* __restrict__ Xh, const f16* __restrict__ Xl,
        const f16* __restrict__ Lh, const f16* __restrict__ Ll,
        float* __restrict__ proj)
{
    __shared__ __attribute__((aligned(16))) char smem[65536];
    const int tid = threadIdx.x;
    const int ct = blockIdx.x, rt = blockIdx.y, ks = blockIdx.z;
    const int r0 = rt*64;
    const int l = tid & 63;
    const int wr = (tid >> 7) & 1, wc = (tid >> 6) & 1;

    const int aswz = (((tid&3) ^ ((tid>>3)&3)) << 3);
    const f16* aSrcH = Xh + (size_t)(r0 + (tid>>2))*SX + 288 + ks*128 + aswz;
    const f16* aSrcL = Xl + (size_t)(r0 + (tid>>2))*SX + 288 + ks*128 + aswz;
    const f16* bSrcH = Lh + (size_t)(ks*4)*10240 + (size_t)ct*2048 + tid*8;
    const f16* bSrcL = Ll + (size_t)(ks*4)*10240 + (size_t)ct*2048 + tid*8;

    int offA[2], offB[2];
#pragma unroll
    for (int R = 0; R < 2; ++R) {
        int g = l >> 4;
        int row = wr*32 + R*16 + (l & 15);
        offA[R] = row*64 + ((g ^ ((row>>1)&3)) & 3)*16;
        int col = wc*32 + R*16 + (l & 15);
        offB[R] = col*64 + ((g ^ ((col>>1)&3)) & 3)*16;
    }
    f32x4 hh[2][2] = {}, hl[2][2] = {}, lh[2][2] = {};

#pragma unroll
    for (int c = 0; c < 4; ++c) {
        char* base = smem + c*16384;
        glds16(aSrcH + c*32, base + tid*16);
        glds16(aSrcL + c*32, base + 4096 + tid*16);
        glds16(bSrcH + (size_t)c*10240, base + 8192 + tid*16);
        glds16(bSrcL + (size_t)c*10240, base + 12288 + tid*16);
    }
    auto computeP = [&](int c) {
        const char* At = smem + c*16384;
        const char* Bt = smem + c*16384 + 8192;
        f16x8 ah[2], al[2], bh[2], bl[2];
#pragma unroll
        for (int R = 0; R < 2; ++R) {
            ah[R] = *(const f16x8*)(At + offA[R]);
            al[R] = *(const f16x8*)(At + 4096 + offA[R]);
            bh[R] = *(const f16x8*)(Bt + offB[R]);
            bl[R] = *(const f16x8*)(Bt + 4096 + offB[R]);
        }
#pragma unroll
        for (int R = 0; R < 2; ++R)
#pragma unroll
            for (int C = 0; C < 2; ++C) {
                hh[R][C] = MFMA16(ah[R], bh[C], hh[R][C]);
                hl[R][C] = MFMA16(ah[R], bl[C], hl[R][C]);
                lh[R][C] = MFMA16(al[R], bh[C], lh[R][C]);
            }
    };
    WAIT_BAR(12); computeP(0);
    WAIT_BAR(8);  computeP(1);
    WAIT_BAR(4);  computeP(2);
    WAIT_BAR(0);  computeP(3);

    float* pout = proj + (size_t)ks*81920;
#pragma unroll
    for (int R = 0; R < 2; ++R)
#pragma unroll
        for (int C = 0; C < 2; ++C) {
            f32x4 d = hh[R][C] + (hl[R][C] + lh[R][C]) * LOINV;
            int col = ct*64 + wc*32 + C*16 + (l & 15);
            int rb = r0 + wr*32 + R*16 + ((l >> 4) << 2);
#pragma unroll
            for (int j = 0; j < 4; ++j)
                pout[(size_t)(rb + j)*320 + col] = d[j];
        }
}

// ---------------- k2b: reduce proj + frame update -> out, X-next frame ----------------
__global__ __launch_bounds__(256) void k2b(const float* __restrict__ fprev,
                                           const float* __restrict__ proj,
                                           const float* __restrict__ l2b,
                                           float* __restrict__ outT,
                                           f16* __restrict__ XhN,
                                           f16* __restrict__ XlN) {
    int idx = blockIdx.x*256 + threadIdx.x;
    if (idx >= 256*288) return;
    int b = idx / 288, f = idx - b*288;
    if (f < Fsz) {
        float v = fprev[(size_t)b*TFs + f] + l2b[f];
#pragma unroll
        for (int ks = 0; ks < 8; ++ks) v += proj[(size_t)ks*81920 + b*320 + f];
        outT[(size_t)b*TFs + f] = v;
        split16(v, XhN[(size_t)b*SX + f], XlN[(size_t)b*SX + f]);
    } else {
        XhN[(size_t)b*SX + f] = (f16)0.f;
        XlN[(size_t)b*SX + f] = (f16)0.f;
    }
}

extern "C" void kernel_launch(void* const* d_in, const int* in_sizes, int n_in,
                              void* d_out_v, int out_size, void* d_ws, size_t ws_size,
                              hipStream_t stream) {
    const float* motions = (const float*)d_in[0];
    const float* temb    = (const float*)d_in[1];
    const float* ltw     = (const float*)d_in[2];   // (512,768)
    const float* ltb     = (const float*)d_in[3];
    const float* l1w     = (const float*)d_in[4];   // (512,263)
    const float* l1b     = (const float*)d_in[5];
    const float* wih     = (const float*)d_in[6];   // (4096,1024)
    const float* whh     = (const float*)d_in[7];   // (4096,1024)
    const float* bih     = (const float*)d_in[8];
    const float* bhh     = (const float*)d_in[9];
    const float* l2w     = (const float*)d_in[10];  // (263,1024)
    const float* l2b     = (const float*)d_in[11];
    float* out = (float*)d_out_v;
    char* ws = (char*)d_ws;
    if (ws_size < (size_t)WS_BYTES) return;

    f16*   Wpk    = (f16*)(ws + OFF_WPK);
    float* cSt    = (float*)(ws + OFF_CST);
    float* cgp    = (float*)(ws + OFF_CGP);
    float* proj   = (float*)(ws + OFF_PROJ);
    f16*   L2h    = (f16*)(ws + OFF_L2PH);
    f16*   L2l    = (f16*)(ws + OFF_L2PL);
    f16*   XhB[2] = { (f16*)(ws + OFF_XHI0), (f16*)(ws + OFF_XHI1) };
    f16*   XlB[2] = { (f16*)(ws + OFF_XLO0), (f16*)(ws + OFF_XLO1) };
    // precompute aliases (dead before region's loop user)
    float* WihT  = (float*)(ws + OFF_WPK);
    float* Wcomb = (float*)(ws + OFF_WCOMB);
    float* cgj   = (float*)(ws + OFF_CGJ);
    float* WcT   = (float*)(ws + OFF_WCT);
    float* lin1t = (float*)(ws + OFF_PROJ);
    float* biasG = (float*)(ws + OFF_PROJ + 538624u);
    float* ltwT  = (float*)(ws + OFF_XHI0);
    float* textE = (float*)(ws + OFF_XLO1);

    dim3 blk(256);
    tpose<<<dim3(32,128), blk, 0, stream>>>(wih, WihT, 4096, 1024);
    tpose<<<dim3(24, 16), blk, 0, stream>>>(ltw, ltwT, 512, 768);
    tpose<<<dim3( 9, 16), blk, 0, stream>>>(l1w, lin1t, 512, 263);
    biasg_k<<<1024, blk, 0, stream>>>(bih, bhh, l1b, wih, biasG);
    nn_gemm<<<dim3( 8, 8), blk, 0, stream>>>(temb, ltwT, ltb, textE, 256, 256, 512, 768);
    nn_gemm<<<dim3(64, 9), blk, 0, stream>>>(lin1t, WihT, nullptr, Wcomb, 288, 263, 4096, 512);
    nn_gemm<<<dim3(64, 8), blk, 0, stream>>>(textE, WihT + (size_t)512*4096, biasG, cgj,
                                             256, 256, 4096, 512);
    tpose<<<dim3(128, 9), blk, 0, stream>>>(Wcomb, WcT, 288, 4096);
    pack_w<<<dim3(128, 41), blk, 0, stream>>>(WcT, whh, Wpk);
    permute_cg<<<4096, blk, 0, stream>>>(cgj, cgp);
    pack_lin2<<<dim3(5, 32), blk, 0, stream>>>(l2w, L2h, L2l);
    init_k<<<2336, blk, 0, stream>>>(motions, XhB[0], XlB[0], cSt);

    for (int t = 0; t < Tsz; ++t) {
        f16* Xhc = XhB[t & 1],      *Xlc = XlB[t & 1];
        f16* Xhn = XhB[(t+1) & 1],  *Xln = XlB[(t+1) & 1];
        const float* fprev = (t == 0) ? motions : (out + (size_t)(t-1)*Fsz);
        k1_gates<<<dim3(128, 4), blk, 0, stream>>>(Xhc, Xlc, Wpk, cgp, cSt, Xhn, Xln);
        k3_proj<<<dim3(5, 4, 8), blk, 0, stream>>>(Xhn, Xln, L2h, L2l, proj);
        k2b<<<288, blk, 0, stream>>>(fprev, proj, l2b, out + (size_t)t*Fsz, Xhn, Xln);
    }
}